// Round 7
// baseline (380.965 us; speedup 1.0000x reference)
//
#include <hip/hip_runtime.h>
#include <hip/hip_bf16.h>
#include <math.h>

#define NN 200000
#define NE 200000

typedef __attribute__((ext_vector_type(8))) short bf16x8;
typedef __attribute__((ext_vector_type(4))) float f32x4;

#define XASTR 136   // XA row stride (u16): mem[n] 128 + node id at [128..129]
#define XBSTR 296   // XB row stride (u16): other(128)|ef(128)|te(16)|zero(16)
#define OSTR  132   // f32 output-stage row stride (XB reuse)
#define RSZ   (32 * XASTR + 32 * XBSTR)   // 13824 u16 = 27648 B = 27 chunks of 1 KB
#define BUFU  14336                       // 28 chunks (1 KB pad) per LDS buffer, u16
#define GRIDB 512                         // persistent blocks for k_main4

__device__ __forceinline__ float sigm(float x) { return 1.0f / (1.0f + __expf(-x)); }
__device__ __forceinline__ float tanh_f(float x) {
    float e = __expf(2.0f * x);
    return 1.0f - 2.0f / (e + 1.0f);
}

__device__ __forceinline__ ushort f2b(float x) {
    union { __hip_bfloat16 b; ushort u; } v;
    v.b = __float2bfloat16(x);
    return v.u;
}
__device__ __forceinline__ float b2f(ushort u) {
    return __uint_as_float(((unsigned)u) << 16);
}
__device__ __forceinline__ ushort4 cvt4(float4 v) {
    ushort4 u; u.x = f2b(v.x); u.y = f2b(v.y); u.z = f2b(v.z); u.w = f2b(v.w);
    return u;
}
__device__ __forceinline__ void gload_lds16(const ushort* g, ushort* l) {
    __builtin_amdgcn_global_load_lds(
        (const __attribute__((address_space(1))) unsigned int*)g,
        (__attribute__((address_space(3))) unsigned int*)l, 16, 0, 0);
}

#define MFMA16(a, b, c) __builtin_amdgcn_mfma_f32_16x16x32_bf16((a), (b), (c), 0, 0, 0)
#define BARSYNC() do { asm volatile("s_waitcnt lgkmcnt(0)" ::: "memory"); \
                       __builtin_amdgcn_s_barrier(); } while (0)

// ================= K2: compose (blocks 0..191) | scatter (blocks 192..) =================
// compose: CW[col][j] = sum_k W2[j][k]*Wih[col][k];  cb = b2@WI^T + bih
#define NB_COMPOSE 192
#define NB_SCATTER (((2 * NE) + 255) / 256)
__global__ void k_pre1(const float* __restrict__ W2, const float* __restrict__ Wih,
                       const float* __restrict__ b2, const float* __restrict__ bih,
                       float* __restrict__ CW, float* __restrict__ cb,
                       const int* __restrict__ src, const int* __restrict__ dst,
                       int* __restrict__ last_pos) {
    int b = blockIdx.x;
    if (b < NB_COMPOSE) {
        int i = b * 256 + threadIdx.x;   // < 384*128 exactly
        int col = i >> 7, j = i & 127;
        float s = 0.0f;
        for (int k = 0; k < 128; ++k) s = fmaf(W2[j * 128 + k], Wih[col * 128 + k], s);
        CW[i] = s;
        if (i < 384) {
            float s2 = bih[i];
            for (int k = 0; k < 128; ++k) s2 = fmaf(b2[k], Wih[i * 128 + k], s2);
            cb[i] = s2;
        }
        return;
    }
    int i = (b - NB_COMPOSE) * 256 + threadIdx.x;
    if (i < NE) {
        atomicMax(&last_pos[src[i]], i);
    } else if (i < 2 * NE) {
        atomicMax(&last_pos[dst[i - NE]], i);
    }
}

// ================= K3: prepfrag (blocks 0..591) | compact (blocks 592..) =================
#define NB_PREP 592      // (104+96+96)*512 / 256
#define NB_COMPACT ((NN + 255) / 256)
__global__ void k_pre2(const float* __restrict__ W1, const float* __restrict__ CW,
                       const float* __restrict__ Whh,
                       ushort* __restrict__ W1F, ushort* __restrict__ W2IF,
                       ushort* __restrict__ WHF,
                       const int* __restrict__ last_pos,
                       const int* __restrict__ src, const int* __restrict__ dst,
                       const float* __restrict__ ts, const float* __restrict__ lut,
                       int4* __restrict__ einfo, int* __restrict__ cnt) {
    int b = blockIdx.x;
    if (b < NB_PREP) {
        int t = b * 256 + threadIdx.x;
        int f = t >> 9;
        int idx = t & 511;
        int lane = idx >> 3, j = idx & 7;
        int c16 = lane & 15, k8 = lane >> 4;
        if (f < 104) {
            int wv = f / 26, r = f % 26;
            int kt = r >> 1, ns = r & 1;
            int col = wv * 32 + ns * 16 + c16;
            int kk = kt * 32 + k8 * 8 + j;
            W1F[t] = (kk < 400) ? f2b(W1[kk * 128 + col]) : (ushort)0;
            return;
        }
        f -= 104;
        if (f < 96) {
            int wv = f / 24, r = f % 24;
            int kt = r / 6, rem = r % 6, g = rem >> 1, ns = rem & 1;
            int col = g * 128 + wv * 32 + ns * 16 + c16;
            int kk = kt * 32 + k8 * 8 + j;
            W2IF[f * 512 + idx] = f2b(CW[col * 128 + kk]);
            return;
        }
        f -= 96;
        int wv = f / 24, r = f % 24;
        int kt = r / 6, rem = r % 6, g = rem >> 1, ns = rem & 1;
        int col = g * 128 + wv * 32 + ns * 16 + c16;
        int kk = kt * 32 + k8 * 8 + j;
        WHF[f * 512 + idx] = f2b(Whh[col * 128 + kk]);
        return;
    }
    int n = (b - NB_PREP) * 256 + threadIdx.x;
    if (n >= NN) return;
    int p = last_pos[n];
    if (p < 0) return;
    int e, other;
    if (p < NE) { e = p;      other = dst[e]; }
    else        { e = p - NE; other = src[e]; }
    float dt = ts[e] - lut[n];
    int idx = atomicAdd(cnt, 1);
    einfo[idx] = make_int4(n, e, other, __float_as_int(dt));
}

// ===== K4: gather 2 rows/wave (blocks 0..24999) | copy-absent (blocks 25000..) =====
#define NB_G 25000   // 8 rows/block covers NN
#define NB_A 25000   // NN*32 threads / 256
__global__ __launch_bounds__(256)
void k_gana(const int4* __restrict__ einfo, const int* __restrict__ cnt_p,
            const int* __restrict__ last_pos,
            const float* __restrict__ mem, const float* __restrict__ ef,
            const float* __restrict__ tw, const float* __restrict__ tphi,
            ushort* __restrict__ P, float* __restrict__ out)
{
    if (blockIdx.x >= NB_G) {
        int t = (blockIdx.x - NB_G) * 256 + threadIdx.x;
        int node = t >> 5;
        if (node >= NN) return;
        if (last_pos[node] < 0) {
            int cc = (t & 31) * 4;
            *(float4*)&out[(size_t)node * 128 + cc] = *(const float4*)&mem[(size_t)node * 128 + cc];
        }
        return;
    }
    const int cnt = *cnt_p;
    const int R32 = (cnt + 31) & ~31;
    const int wv   = threadIdx.x >> 6;
    const int lane = threadIdx.x & 63;
    const int w = blockIdx.x * 4 + wv;
    const int r0 = w * 2, r1 = r0 + 1;
    if (r0 >= R32) return;
    const bool pA = r0 < cnt, pB = r1 < cnt;
    int4 eiA = make_int4(0, 0, 0, 0), eiB = make_int4(0, 0, 0, 0);
    if (pA) eiA = einfo[r0];
    if (pB) eiB = einfo[r1];
    float4 fA0 = {0,0,0,0}, fA1 = {0,0,0,0}, fB0 = {0,0,0,0}, fB1 = {0,0,0,0};
    float teA = 0.0f, teB = 0.0f;
    const int l = lane - 32;
    if (lane < 32) {
        if (pA) { fA0 = *(const float4*)&mem[(size_t)eiA.x * 128 + lane * 4];
                  fA1 = *(const float4*)&ef [(size_t)eiA.y * 128 + lane * 4]; }
        if (pB) { fB0 = *(const float4*)&mem[(size_t)eiB.x * 128 + lane * 4];
                  fB1 = *(const float4*)&ef [(size_t)eiB.y * 128 + lane * 4]; }
    } else {
        if (pA) { fA0 = *(const float4*)&mem[(size_t)eiA.z * 128 + l * 4];
                  if (l < 16) {
                      float wt = fmaf(__int_as_float(eiA.w), tw[l], tphi[l]);
                      teA = (l == 0) ? wt : __sinf(wt);
                  } }
        if (pB) { fB0 = *(const float4*)&mem[(size_t)eiB.z * 128 + l * 4];
                  if (l < 16) {
                      float wt = fmaf(__int_as_float(eiB.w), tw[l], tphi[l]);
                      teB = (l == 0) ? wt : __sinf(wt);
                  } }
    }
    {   // write row r0
        ushort* xa = P + (size_t)(r0 >> 5) * RSZ + (r0 & 31) * XASTR;
        ushort* xb = P + (size_t)(r0 >> 5) * RSZ + 32 * XASTR + (r0 & 31) * XBSTR;
        if (lane < 32) {
            *(ushort4*)&xa[lane * 4] = cvt4(fA0);
            *(ushort4*)&xb[128 + lane * 4] = cvt4(fA1);
            if (lane == 0) *(unsigned*)&xa[128] = (unsigned)eiA.x;
        } else {
            *(ushort4*)&xb[l * 4] = cvt4(fA0);
            if (l < 32) xb[256 + l] = (l < 16) ? f2b(teA) : (ushort)0;
        }
    }
    if (r1 < R32) {   // write row r1
        ushort* xa = P + (size_t)(r1 >> 5) * RSZ + (r1 & 31) * XASTR;
        ushort* xb = P + (size_t)(r1 >> 5) * RSZ + 32 * XASTR + (r1 & 31) * XBSTR;
        if (lane < 32) {
            *(ushort4*)&xa[lane * 4] = cvt4(fB0);
            *(ushort4*)&xb[128 + lane * 4] = cvt4(fB1);
            if (lane == 0) *(unsigned*)&xa[128] = (unsigned)eiB.x;
        } else {
            *(ushort4*)&xb[l * 4] = cvt4(fB0);
            if (l < 32) xb[256 + l] = (l < 16) ? f2b(teB) : (ushort)0;
        }
    }
}

// ===== K5: persistent double-buffered main (counted vmcnt, raw barriers) =====
__device__ __forceinline__ void stage_tile(const ushort* __restrict__ P, int t,
                                           ushort* dst, int wv, int lane) {
    const ushort* src = P + (size_t)t * RSZ;
    #pragma unroll
    for (int c2 = 0; c2 < 7; ++c2) {
        int cc = wv + c2 * 4;                 // 0..27 — uniform 7 chunks per wave
        gload_lds16(src + cc * 512 + lane * 8, dst + cc * 512);
    }
}

__global__ __launch_bounds__(256, 2)
void k_main4(const ushort* __restrict__ P, const int* __restrict__ cnt_p,
             const ushort* __restrict__ W1F, const float* __restrict__ b1,
             const ushort* __restrict__ W2IF, const ushort* __restrict__ WHF,
             const float* __restrict__ cb, const float* __restrict__ bhh,
             float* __restrict__ out)
{
    __shared__ __align__(16) ushort LDS[2 * BUFU];
    const int cnt = *cnt_p;
    const int NT  = (cnt + 31) >> 5;
    int t = blockIdx.x;
    if (t >= NT) return;
    const int tid  = threadIdx.x;
    const int lane = tid & 63;
    const int wv   = tid >> 6;
    const int r16  = lane & 15;
    const int kb   = lane >> 4;

    // hoisted per-thread biases (constant across tiles)
    float b1v[2], brz0[2], brz1[2], binv[2], bhnv[2];
    #pragma unroll
    for (int ns = 0; ns < 2; ++ns) {
        int col = wv * 32 + ns * 16 + r16;
        b1v[ns]  = b1[col];
        brz0[ns] = cb[col] + bhh[col];
        brz1[ns] = cb[128 + col] + bhh[128 + col];
        binv[ns] = cb[256 + col];
        bhnv[ns] = bhh[256 + col];
    }
    const ushort* w1 = W1F  + wv * (26 * 512) + lane * 8;
    const ushort* wI = W2IF + wv * (24 * 512) + lane * 8;
    const ushort* wH = WHF  + wv * (24 * 512) + lane * 8;

    stage_tile(P, t, &LDS[0], wv, lane);   // prologue prefetch
    int c = 0;
    for (; t < NT; t += GRIDB) {
        ushort* XA = &LDS[c * BUFU];
        ushort* XB = XA + 32 * XASTR;
        const int tn = t + GRIDB;

        // T0: all prev-iteration LDS reads done before restaging the other buffer
        BARSYNC();
        if (tn < NT) {
            stage_tile(P, tn, &LDS[(c ^ 1) * BUFU], wv, lane);
            asm volatile("s_waitcnt vmcnt(7)" ::: "memory");   // 7 newest = prefetch; buf[c] done
        } else {
            asm volatile("s_waitcnt vmcnt(0)" ::: "memory");
        }
        __builtin_amdgcn_sched_barrier(0);
        __builtin_amdgcn_s_barrier();      // buf[c] visible to all waves

        // ---- C1: layer 1  h1 = relu(x @ W1 + b1), M=32 N=128 K=416 ----
        f32x4 c1[2][2] = {};
        {
            const ushort* aA = &XA[r16 * XASTR + kb * 8];
            const ushort* aB = &XB[r16 * XBSTR + kb * 8];
            #pragma unroll
            for (int kt = 0; kt < 13; ++kt) {
                const ushort* ap  = (kt < 4) ? (aA + kt * 32) : (aB + (kt - 4) * 32);
                const int     ast = (kt < 4) ? XASTR : XBSTR;
                bf16x8 A0 = *(const bf16x8*)ap;
                bf16x8 A1 = *(const bf16x8*)(ap + 16 * ast);
                bf16x8 B0 = *(const bf16x8*)(w1 + (kt * 2 + 0) * 512);
                bf16x8 B1 = *(const bf16x8*)(w1 + (kt * 2 + 1) * 512);
                c1[0][0] = MFMA16(A0, B0, c1[0][0]);
                c1[0][1] = MFMA16(A0, B1, c1[0][1]);
                c1[1][0] = MFMA16(A1, B0, c1[1][0]);
                c1[1][1] = MFMA16(A1, B1, c1[1][1]);
            }
        }
        BARSYNC();   // all X reads done; safe to overwrite XB cols 0..127 with H

        // ---- C2: H write ----
        #pragma unroll
        for (int ns = 0; ns < 2; ++ns) {
            int col = wv * 32 + ns * 16 + r16;
            #pragma unroll
            for (int m = 0; m < 2; ++m)
                #pragma unroll
                for (int r = 0; r < 4; ++r)
                    XB[(m * 16 + kb * 4 + r) * XBSTR + col] =
                        f2b(fmaxf(c1[m][ns][r] + b1v[ns], 0.0f));
        }
        BARSYNC();

        // ---- C3: GRU (composed): gi = h1 @ CW-frags, gh = h @ WH-frags ----
        f32x4 arz[2][4] = {};
        f32x4 an_i[2][2] = {};
        f32x4 an_h[2][2] = {};
        {
            const ushort* am = &XB[r16 * XBSTR + kb * 8];
            const ushort* ah = &XA[r16 * XASTR + kb * 8];
            #pragma unroll
            for (int kt = 0; kt < 4; ++kt) {
                bf16x8 M0 = *(const bf16x8*)(am + kt * 32);
                bf16x8 M1 = *(const bf16x8*)(am + 16 * XBSTR + kt * 32);
                bf16x8 H0 = *(const bf16x8*)(ah + kt * 32);
                bf16x8 H1 = *(const bf16x8*)(ah + 16 * XASTR + kt * 32);
                #pragma unroll
                for (int g = 0; g < 2; ++g)
                    #pragma unroll
                    for (int ns = 0; ns < 2; ++ns) {
                        int fo = (kt * 6 + g * 2 + ns) * 512;
                        bf16x8 Bi = *(const bf16x8*)(wI + fo);
                        bf16x8 Bh = *(const bf16x8*)(wH + fo);
                        arz[0][g * 2 + ns] = MFMA16(M0, Bi, arz[0][g * 2 + ns]);
                        arz[0][g * 2 + ns] = MFMA16(H0, Bh, arz[0][g * 2 + ns]);
                        arz[1][g * 2 + ns] = MFMA16(M1, Bi, arz[1][g * 2 + ns]);
                        arz[1][g * 2 + ns] = MFMA16(H1, Bh, arz[1][g * 2 + ns]);
                    }
                #pragma unroll
                for (int ns = 0; ns < 2; ++ns) {
                    int fo = (kt * 6 + 4 + ns) * 512;
                    bf16x8 Bi = *(const bf16x8*)(wI + fo);
                    bf16x8 Bh = *(const bf16x8*)(wH + fo);
                    an_i[0][ns] = MFMA16(M0, Bi, an_i[0][ns]);
                    an_i[1][ns] = MFMA16(M1, Bi, an_i[1][ns]);
                    an_h[0][ns] = MFMA16(H0, Bh, an_h[0][ns]);
                    an_h[1][ns] = MFMA16(H1, Bh, an_h[1][ns]);
                }
            }
        }
        BARSYNC();   // H/h reads done; XB reusable as f32 out-stage

        // ---- C4: gates + blend -> f32 stage in LDS ----
        float* XBf = (float*)XB;
        #pragma unroll
        for (int ns = 0; ns < 2; ++ns) {
            int col = wv * 32 + ns * 16 + r16;
            #pragma unroll
            for (int m = 0; m < 2; ++m) {
                #pragma unroll
                for (int r = 0; r < 4; ++r) {
                    int row = m * 16 + kb * 4 + r;
                    float rr = sigm(arz[m][0 + ns][r] + brz0[ns]);
                    float zz = sigm(arz[m][2 + ns][r] + brz1[ns]);
                    float nn = tanh_f(an_i[m][ns][r] + binv[ns] +
                                      rr * (an_h[m][ns][r] + bhnv[ns]));
                    float hh = b2f(XA[row * XASTR + col]);
                    XBf[row * OSTR + col] = (1.0f - zz) * nn + zz * hh;
                }
            }
        }
        BARSYNC();

        // ---- C5: coalesced store, one wave per full 512 B row ----
        const int nt = min(32, cnt - t * 32);
        for (int j = wv; j < nt; j += 4) {
            unsigned node = *(const unsigned*)&XA[j * XASTR + 128];
            float2 v = *(const float2*)&XBf[j * OSTR + lane * 2];
            *(float2*)&out[(size_t)node * 128 + lane * 2] = v;
        }
        c ^= 1;
    }
}

extern "C" void kernel_launch(void* const* d_in, const int* in_sizes, int n_in,
                              void* d_out, int out_size, void* d_ws, size_t ws_size,
                              hipStream_t stream) {
    const int*   src  = (const int*)d_in[0];
    const int*   dst  = (const int*)d_in[1];
    const float* ef   = (const float*)d_in[2];
    const float* ts   = (const float*)d_in[3];
    const float* mem  = (const float*)d_in[4];
    const float* lut  = (const float*)d_in[5];
    const float* tw   = (const float*)d_in[6];
    const float* tphi = (const float*)d_in[7];
    const float* W1   = (const float*)d_in[8];
    const float* b1   = (const float*)d_in[9];
    const float* W2   = (const float*)d_in[10];
    const float* b2   = (const float*)d_in[11];
    const float* Wih  = (const float*)d_in[12];
    const float* Whh  = (const float*)d_in[13];
    const float* bih  = (const float*)d_in[14];
    const float* bhh  = (const float*)d_in[15];
    float* out = (float*)d_out;

    char* ws = (char*)d_ws;
    size_t off = 0;
    int*    last_pos = (int*)(ws + off);    off += (size_t)NN * 4;
    int4*   einfo    = (int4*)(ws + off);   off += (size_t)NN * 16;
    int*    cnt      = (int*)(ws + off);    off += 16;
    float*  CW       = (float*)(ws + off);  off += (size_t)384 * 128 * 4;
    float*  cb       = (float*)(ws + off);  off += (size_t)384 * 4 + 16;
    ushort* W1F      = (ushort*)(ws + off); off += (size_t)104 * 512 * 2;
    ushort* W2IF     = (ushort*)(ws + off); off += (size_t)96 * 512 * 2;
    ushort* WHF      = (ushort*)(ws + off); off += (size_t)96 * 512 * 2;
    ushort* P        = (ushort*)(ws + off);   // 6250*RSZ*2 B + 2 KB slack

    hipMemsetAsync(last_pos, 0xFF, (size_t)NN * sizeof(int), stream);  // -1
    hipMemsetAsync(cnt, 0, sizeof(int), stream);

    k_pre1<<<NB_COMPOSE + NB_SCATTER, 256, 0, stream>>>(
        W2, Wih, b2, bih, CW, cb, src, dst, last_pos);
    k_pre2<<<NB_PREP + NB_COMPACT, 256, 0, stream>>>(
        W1, CW, Whh, W1F, W2IF, WHF, last_pos, src, dst, ts, lut, einfo, cnt);
    k_gana<<<NB_G + NB_A, 256, 0, stream>>>(
        einfo, cnt, last_pos, mem, ef, tw, tphi, P, out);
    k_main4<<<GRIDB, 256, 0, stream>>>(
        P, cnt, W1F, b1, W2IF, WHF, cb, bhh, out);
}

// Round 8
// 270.499 us; speedup vs baseline: 1.4084x; 1.4084x over previous
//
#include <hip/hip_runtime.h>
#include <hip/hip_bf16.h>
#include <math.h>

#define NN 200000
#define NE 200000

typedef __attribute__((ext_vector_type(8))) short bf16x8;
typedef __attribute__((ext_vector_type(4))) float f32x4;

#define XASTR 136   // XA row stride (u16): mem[n] bf16, 128 used
#define XBSTR 296   // XB/PB row stride (u16): other(128)|ef(128)|te(16)|zero(16)|pad(8)
#define OSTR  132   // f32 output-stage row stride (XB reuse)
#define NT    (NN / 32)            // 6250 tiles, exact
#define PBT   (32 * XBSTR)         // 9472 u16 = 18944 B per tile

__device__ __forceinline__ float sigm(float x) { return 1.0f / (1.0f + __expf(-x)); }
__device__ __forceinline__ float tanh_f(float x) {
    float e = __expf(2.0f * x);
    return 1.0f - 2.0f / (e + 1.0f);
}
__device__ __forceinline__ ushort f2b(float x) {
    union { __hip_bfloat16 b; ushort u; } v;
    v.b = __float2bfloat16(x);
    return v.u;
}
__device__ __forceinline__ float b2f(ushort u) {
    return __uint_as_float(((unsigned)u) << 16);
}
__device__ __forceinline__ ushort4 cvt4(float4 v) {
    ushort4 u; u.x = f2b(v.x); u.y = f2b(v.y); u.z = f2b(v.z); u.w = f2b(v.w);
    return u;
}
__device__ __forceinline__ void gload_lds16(const ushort* g, ushort* l) {
    __builtin_amdgcn_global_load_lds(
        (const __attribute__((address_space(1))) unsigned int*)g,
        (__attribute__((address_space(3))) unsigned int*)l, 16, 0, 0);
}

#define MFMA16(a, b, c) __builtin_amdgcn_mfma_f32_16x16x32_bf16((a), (b), (c), 0, 0, 0)

// ======== K1: weight prep — W1F pack, W2IF = (W2·Wih^T) pack (inline dot), WHF pack, cb ========
__global__ void k_prep(const float* __restrict__ W1, const float* __restrict__ W2,
                       const float* __restrict__ Wih, const float* __restrict__ Whh,
                       const float* __restrict__ b2, const float* __restrict__ bih,
                       ushort* __restrict__ W1F, ushort* __restrict__ W2IF,
                       ushort* __restrict__ WHF, float* __restrict__ cb) {
    int t = blockIdx.x * 256 + threadIdx.x;
    if (t < 104 * 512) {
        int f = t >> 9, idx = t & 511;
        int lane = idx >> 3, j = idx & 7, c16 = lane & 15, k8 = lane >> 4;
        int wvv = f / 26, r = f % 26, kt = r >> 1, ns = r & 1;
        int col = wvv * 32 + ns * 16 + c16;
        int kk = kt * 32 + k8 * 8 + j;
        W1F[t] = (kk < 400) ? f2b(W1[kk * 128 + col]) : (ushort)0;
        return;
    }
    t -= 104 * 512;
    if (t < 96 * 512) {
        int f = t >> 9, idx = t & 511;
        int lane = idx >> 3, j = idx & 7, c16 = lane & 15, k8 = lane >> 4;
        int wvv = f / 24, r = f % 24, kt = r / 6, rem = r % 6, g = rem >> 1, ns = rem & 1;
        int col = g * 128 + wvv * 32 + ns * 16 + c16;
        int kk = kt * 32 + k8 * 8 + j;
        float s = 0.0f;
        for (int c = 0; c < 128; ++c) s = fmaf(W2[kk * 128 + c], Wih[col * 128 + c], s);
        W2IF[f * 512 + idx] = f2b(s);
        return;
    }
    t -= 96 * 512;
    if (t < 96 * 512) {
        int f = t >> 9, idx = t & 511;
        int lane = idx >> 3, j = idx & 7, c16 = lane & 15, k8 = lane >> 4;
        int wvv = f / 24, r = f % 24, kt = r / 6, rem = r % 6, g = rem >> 1, ns = rem & 1;
        int col = g * 128 + wvv * 32 + ns * 16 + c16;
        int kk = kt * 32 + k8 * 8 + j;
        WHF[f * 512 + idx] = f2b(Whh[col * 128 + kk]);
        return;
    }
    t -= 96 * 512;
    if (t < 384) {
        float s = bih[t];
        for (int k = 0; k < 128; ++k) s = fmaf(b2[k], Wih[t * 128 + k], s);
        cb[t] = s;
    }
}

// ======== K2: last_pos via atomicMax (== segment_max of positions) ========
__global__ void k_scatter(const int* __restrict__ src, const int* __restrict__ dst,
                          int* __restrict__ last_pos) {
    int i = blockIdx.x * blockDim.x + threadIdx.x;
    if (i < NE) {
        atomicMax(&last_pos[src[i]], i);
    } else if (i < 2 * NE) {
        atomicMax(&last_pos[dst[i - NE]], i);
    }
}

// ======== K3: gather random operands -> PB[n] (resolve inlined, wave-uniform) ========
__global__ __launch_bounds__(256)
void k_gath(const int* __restrict__ last_pos,
            const int* __restrict__ src, const int* __restrict__ dst,
            const float* __restrict__ ts, const float* __restrict__ lut,
            const float* __restrict__ mem, const float* __restrict__ ef,
            const float* __restrict__ tw, const float* __restrict__ tphi,
            ushort* __restrict__ PB)
{
    const int wv = threadIdx.x >> 6, lane = threadIdx.x & 63;
    const int n0 = (blockIdx.x * 4 + wv) * 2;
    const int l = lane - 32;
    #pragma unroll
    for (int s = 0; s < 2; ++s) {
        int n = n0 + s;
        int p = last_pos[n];
        if (p < 0) continue;
        int e     = (p < NE) ? p : p - NE;
        int other = (p < NE) ? dst[e] : src[e];
        ushort* xb = PB + (size_t)n * XBSTR;
        if (lane < 32) {
            float4 v = *(const float4*)&mem[(size_t)other * 128 + lane * 4];
            *(ushort4*)&xb[lane * 4] = cvt4(v);
            float val = 0.0f;
            if (lane < 16) {
                float dt = ts[e] - lut[n];
                float wt = fmaf(dt, tw[lane], tphi[lane]);
                val = (lane == 0) ? wt : __sinf(wt);
            }
            xb[256 + lane] = f2b(val);   // te(16) + zeros(16)
        } else {
            float4 w = *(const float4*)&ef[(size_t)e * 128 + l * 4];
            *(ushort4*)&xb[128 + l * 4] = cvt4(w);
        }
    }
}

// ======== K4: main — tile = 32 consecutive nodes; sequential mem/out, PB via gload_lds ========
__global__ __launch_bounds__(256, 4)
void k_main5(const ushort* __restrict__ PB, const int* __restrict__ last_pos,
             const float* __restrict__ mem,
             const ushort* __restrict__ W1F, const float* __restrict__ b1,
             const ushort* __restrict__ W2IF, const ushort* __restrict__ WHF,
             const float* __restrict__ cb, const float* __restrict__ bhh,
             float* __restrict__ out)
{
    __shared__ __align__(16) ushort XA[32 * XASTR];
    __shared__ __align__(16) ushort XB[32 * XBSTR + 256];   // +512B guard for tail chunk
    __shared__ unsigned char pres[32];

    const int base = blockIdx.x * 32;
    const int tid  = threadIdx.x;
    const int lane = tid & 63;
    const int wv   = tid >> 6;
    const int r16  = lane & 15;
    const int kb   = lane >> 4;

    // ---- S1: PB tile -> XB via direct global->LDS (18 full 1KB chunks + one 512B) ----
    {
        const ushort* srcPB = PB + (size_t)blockIdx.x * PBT;
        #pragma unroll
        for (int j = 0; j < 5; ++j) {
            int cc = wv + j * 4;
            if (cc < 18) gload_lds16(srcPB + cc * 512 + lane * 8, XB + cc * 512);
            else if (cc == 18 && lane < 32) gload_lds16(srcPB + cc * 512 + lane * 8, XB + cc * 512);
        }
    }
    // ---- S2: mem rows (sequential, coalesced) -> f32 regs -> bf16 -> XA ----
    {
        const float* msrc = mem + (size_t)base * 128;
        #pragma unroll
        for (int k = 0; k < 4; ++k) {
            int i0 = k * 1024 + tid * 4;
            float4 v = *(const float4*)&msrc[i0];
            int row = i0 >> 7, col = i0 & 127;
            *(ushort4*)&XA[row * XASTR + col] = cvt4(v);
        }
        if (tid < 32) pres[tid] = (unsigned char)(last_pos[base + tid] >= 0);
    }
    // hoisted biases
    float b1v[2], brz0[2], brz1[2], binv[2], bhnv[2];
    #pragma unroll
    for (int ns = 0; ns < 2; ++ns) {
        int col = wv * 32 + ns * 16 + r16;
        b1v[ns]  = b1[col];
        brz0[ns] = cb[col] + bhh[col];
        brz1[ns] = cb[128 + col] + bhh[128 + col];
        binv[ns] = cb[256 + col];
        bhnv[ns] = bhh[256 + col];
    }
    const ushort* w1 = W1F  + wv * (26 * 512) + lane * 8;
    const ushort* wI = W2IF + wv * (24 * 512) + lane * 8;
    const ushort* wH = WHF  + wv * (24 * 512) + lane * 8;
    __syncthreads();

    // ---- C1: layer 1  h1 = relu(x @ W1 + b1), M=32 N=128 K=416 ----
    f32x4 c1[2][2] = {};
    {
        const ushort* aA = &XA[r16 * XASTR + kb * 8];
        const ushort* aB = &XB[r16 * XBSTR + kb * 8];
        #pragma unroll
        for (int kt = 0; kt < 13; ++kt) {
            const ushort* ap  = (kt < 4) ? (aA + kt * 32) : (aB + (kt - 4) * 32);
            const int     ast = (kt < 4) ? XASTR : XBSTR;
            bf16x8 A0 = *(const bf16x8*)ap;
            bf16x8 A1 = *(const bf16x8*)(ap + 16 * ast);
            bf16x8 B0 = *(const bf16x8*)(w1 + (kt * 2 + 0) * 512);
            bf16x8 B1 = *(const bf16x8*)(w1 + (kt * 2 + 1) * 512);
            c1[0][0] = MFMA16(A0, B0, c1[0][0]);
            c1[0][1] = MFMA16(A0, B1, c1[0][1]);
            c1[1][0] = MFMA16(A1, B0, c1[1][0]);
            c1[1][1] = MFMA16(A1, B1, c1[1][1]);
        }
    }
    __syncthreads();   // all X reads done; safe to overwrite XB cols 0..127 with H

    // ---- C2: H write ----
    #pragma unroll
    for (int ns = 0; ns < 2; ++ns) {
        int col = wv * 32 + ns * 16 + r16;
        #pragma unroll
        for (int m = 0; m < 2; ++m)
            #pragma unroll
            for (int r = 0; r < 4; ++r)
                XB[(m * 16 + kb * 4 + r) * XBSTR + col] =
                    f2b(fmaxf(c1[m][ns][r] + b1v[ns], 0.0f));
    }
    __syncthreads();

    // ---- C3: GRU (composed): gi = h1 @ CW-frags, gh = h @ WH-frags ----
    f32x4 arz[2][4] = {};
    f32x4 an_i[2][2] = {};
    f32x4 an_h[2][2] = {};
    {
        const ushort* am = &XB[r16 * XBSTR + kb * 8];
        const ushort* ah = &XA[r16 * XASTR + kb * 8];
        #pragma unroll
        for (int kt = 0; kt < 4; ++kt) {
            bf16x8 M0 = *(const bf16x8*)(am + kt * 32);
            bf16x8 M1 = *(const bf16x8*)(am + 16 * XBSTR + kt * 32);
            bf16x8 H0 = *(const bf16x8*)(ah + kt * 32);
            bf16x8 H1 = *(const bf16x8*)(ah + 16 * XASTR + kt * 32);
            #pragma unroll
            for (int g = 0; g < 2; ++g)
                #pragma unroll
                for (int ns = 0; ns < 2; ++ns) {
                    int fo = (kt * 6 + g * 2 + ns) * 512;
                    bf16x8 Bi = *(const bf16x8*)(wI + fo);
                    bf16x8 Bh = *(const bf16x8*)(wH + fo);
                    arz[0][g * 2 + ns] = MFMA16(M0, Bi, arz[0][g * 2 + ns]);
                    arz[0][g * 2 + ns] = MFMA16(H0, Bh, arz[0][g * 2 + ns]);
                    arz[1][g * 2 + ns] = MFMA16(M1, Bi, arz[1][g * 2 + ns]);
                    arz[1][g * 2 + ns] = MFMA16(H1, Bh, arz[1][g * 2 + ns]);
                }
            #pragma unroll
            for (int ns = 0; ns < 2; ++ns) {
                int fo = (kt * 6 + 4 + ns) * 512;
                bf16x8 Bi = *(const bf16x8*)(wI + fo);
                bf16x8 Bh = *(const bf16x8*)(wH + fo);
                an_i[0][ns] = MFMA16(M0, Bi, an_i[0][ns]);
                an_i[1][ns] = MFMA16(M1, Bi, an_i[1][ns]);
                an_h[0][ns] = MFMA16(H0, Bh, an_h[0][ns]);
                an_h[1][ns] = MFMA16(H1, Bh, an_h[1][ns]);
            }
        }
    }
    __syncthreads();   // H/h reads done; XB reusable as f32 out-stage

    // ---- C4: gates + blend -> f32 stage in LDS ----
    float* XBf = (float*)XB;
    #pragma unroll
    for (int ns = 0; ns < 2; ++ns) {
        int col = wv * 32 + ns * 16 + r16;
        #pragma unroll
        for (int m = 0; m < 2; ++m) {
            #pragma unroll
            for (int r = 0; r < 4; ++r) {
                int row = m * 16 + kb * 4 + r;
                float rr = sigm(arz[m][0 + ns][r] + brz0[ns]);
                float zz = sigm(arz[m][2 + ns][r] + brz1[ns]);
                float nn = tanh_f(an_i[m][ns][r] + binv[ns] +
                                  rr * (an_h[m][ns][r] + bhnv[ns]));
                float hh = b2f(XA[row * XASTR + col]);
                XBf[row * OSTR + col] = (1.0f - zz) * nn + zz * hh;
            }
        }
    }
    __syncthreads();

    // ---- C5: fully sequential store; absent rows = exact f32 copy of mem ----
    for (int j = wv; j < 32; j += 4) {
        float2 v;
        if (pres[j]) v = *(const float2*)&XBf[j * OSTR + lane * 2];
        else         v = *(const float2*)&mem[(size_t)(base + j) * 128 + lane * 2];
        *(float2*)&out[(size_t)(base + j) * 128 + lane * 2] = v;
    }
}

extern "C" void kernel_launch(void* const* d_in, const int* in_sizes, int n_in,
                              void* d_out, int out_size, void* d_ws, size_t ws_size,
                              hipStream_t stream) {
    const int*   src  = (const int*)d_in[0];
    const int*   dst  = (const int*)d_in[1];
    const float* ef   = (const float*)d_in[2];
    const float* ts   = (const float*)d_in[3];
    const float* mem  = (const float*)d_in[4];
    const float* lut  = (const float*)d_in[5];
    const float* tw   = (const float*)d_in[6];
    const float* tphi = (const float*)d_in[7];
    const float* W1   = (const float*)d_in[8];
    const float* b1   = (const float*)d_in[9];
    const float* W2   = (const float*)d_in[10];
    const float* b2   = (const float*)d_in[11];
    const float* Wih  = (const float*)d_in[12];
    const float* Whh  = (const float*)d_in[13];
    const float* bih  = (const float*)d_in[14];
    const float* bhh  = (const float*)d_in[15];
    float* out = (float*)d_out;

    char* ws = (char*)d_ws;
    size_t off = 0;
    int*    last_pos = (int*)(ws + off);    off += (size_t)NN * 4;
    ushort* W1F      = (ushort*)(ws + off); off += (size_t)104 * 512 * 2;
    ushort* W2IF     = (ushort*)(ws + off); off += (size_t)96 * 512 * 2;
    ushort* WHF      = (ushort*)(ws + off); off += (size_t)96 * 512 * 2;
    float*  cb       = (float*)(ws + off);  off += (size_t)384 * 4 + 64;
    ushort* PB       = (ushort*)(ws + off);   // NN * XBSTR * 2 = 118.4 MB (last region)

    hipMemsetAsync(last_pos, 0xFF, (size_t)NN * sizeof(int), stream);  // -1

    k_prep<<<(104 * 512 + 2 * 96 * 512 + 384 + 255) / 256, 256, 0, stream>>>(
        W1, W2, Wih, Whh, b2, bih, W1F, W2IF, WHF, cb);
    k_scatter<<<(2 * NE + 255) / 256, 256, 0, stream>>>(src, dst, last_pos);
    k_gath<<<NN / 8, 256, 0, stream>>>(last_pos, src, dst, ts, lut, mem, ef, tw, tphi, PB);
    k_main5<<<NT, 256, 0, stream>>>(PB, last_pos, mem, W1F, b1, W2IF, WHF, cb, bhh, out);
}